// Round 7
// baseline (63849.011 us; speedup 1.0000x reference)
//
#include <hip/hip_runtime.h>
#include <stdint.h>

// LSTM (B=128, T=512, I=64, H=512) persistent kernel, round 7:
//  - XCD-LOCAL h exchange (runtime XCC_ID claim, 8 blocks/group on one XCD):
//    plain stores -> local L2, sc0 loads (L1-bypass) -> L2 hit, ~250cy RT
//  - HANG FIXES vs round 6:
//      (1) early-clobber "=&v" on the sc0 pair-load asm (round-6 hang: output
//          could alias the address pair -> poll loop read garbage forever)
//      (2) producers DUAL-STORE (plain + sc1/MALL, byte-identical); consumers
//          poll sc0 with a capped spin -> sticky per-thread sc1 fallback.
//          Forward progress guaranteed even if XCD coherence model is wrong.
//      (3) balance-gated all-sc1 fallback for dispatch anomalies (as r6)
//  - tagged u64 granules {u32 tag, 2xbf16}; poll IS the data load
//  - DPP-paired LDS scatter (0 bank conflicts), masked b128 reads, 4 MFMA chains

#define T_STEPS 512
#define HID 512
#define IND 64
#define NGROUPS 32
#define BPG 8           // blocks per group
#define BATCH_PG 4      // batches per group
#define UPB 64          // hidden units per block
#define NTHREADS 512    // 8 waves
#define NBLK (NGROUPS * BPG)
#define POLL_CAP 65536

typedef float f32x4 __attribute__((ext_vector_type(4)));
typedef short s16x8 __attribute__((ext_vector_type(8)));
typedef unsigned u32x4 __attribute__((ext_vector_type(4)));
typedef unsigned long long u64_t;

#define ALOADU(p)    __hip_atomic_load((p), __ATOMIC_RELAXED, __HIP_MEMORY_SCOPE_AGENT)
#define ASTOREU(p,v) __hip_atomic_store((p), (v), __ATOMIC_RELAXED, __HIP_MEMORY_SCOPE_AGENT)
#define AFADDU(p,v)  __hip_atomic_fetch_add((p), (v), __ATOMIC_RELAXED, __HIP_MEMORY_SCOPE_AGENT)

__device__ inline unsigned short f2bf(float f) {
  uint32_t u = __builtin_bit_cast(uint32_t, f);
  u += 0x7fffu + ((u >> 16) & 1u);   // RNE (finite inputs)
  return (unsigned short)(u >> 16);
}

__device__ inline s16x8 pack8(f32x4 a, f32x4 b) {
  s16x8 r;
  r[0] = (short)f2bf(a[0]); r[1] = (short)f2bf(a[1]);
  r[2] = (short)f2bf(a[2]); r[3] = (short)f2bf(a[3]);
  r[4] = (short)f2bf(b[0]); r[5] = (short)f2bf(b[1]);
  r[6] = (short)f2bf(b[2]); r[7] = (short)f2bf(b[3]);
  return r;
}

template <int CTRL>
__device__ inline float qbc(float v) {   // quad_perm broadcast via DPP (VALU)
  int i = __builtin_bit_cast(int, v);
  return __builtin_bit_cast(float,
      __builtin_amdgcn_update_dpp(i, i, CTRL, 0xF, 0xF, false));
}

__device__ inline unsigned qswap(unsigned v) {  // quad_perm [1,0,3,2]
  int i = __builtin_bit_cast(int, v);
  return (unsigned)__builtin_amdgcn_update_dpp(i, i, 0xB1, 0xF, 0xF, false);
}

// one 16B sc0 load of a granule pair (L1-bypass, local-L2 hit). EARLY-CLOBBER.
__device__ inline void ld_pair_sc0(const u64_t* p, u64_t& a, u64_t& b) {
  u32x4 r;
  asm volatile("global_load_dwordx4 %0, %1, off sc0\n\ts_waitcnt vmcnt(0)"
               : "=&v"(r) : "v"(p) : "memory");
  a = ((u64_t)r[1] << 32) | r[0];
  b = ((u64_t)r[3] << 32) | r[2];
}

// dual store: plain (local L2, fast path) when loc, plus sc1 (MALL truth) always
__device__ inline void st_dual(u64_t* p, bool loc, u64_t v) {
  if (loc)
    asm volatile("global_store_dwordx2 %0, %1, off" :: "v"(p), "v"(v) : "memory");
  ASTOREU(p, v);
}

__global__ void __launch_bounds__(NTHREADS, 2)
lstm_persist(const float* __restrict__ x,   const float* __restrict__ Wih,
             const float* __restrict__ Whh, const float* __restrict__ bih,
             const float* __restrict__ bhh, const float* __restrict__ Wcls,
             const float* __restrict__ bcls, float* __restrict__ out,
             u64_t* __restrict__ hx,        // [2][NGROUPS][1024] granules (kernel-inited)
             unsigned* __restrict__ ctrl)   // [32]: [0..15] xcd claims, [16] bar1, [17] bar2
{
  __shared__ unsigned short hsm[2][4 * HID];      // 2 x 4KB A-tile (rows 0..3)
  __shared__ float clsh[BATCH_PG][UPB];           // final-h for classifier
  __shared__ int s_g, s_blk, s_loc;

  const int tid  = threadIdx.x;
  const int w    = tid >> 6;
  const int lane = tid & 63;
  const int lrow = lane & 15;   // A row / D col
  const int lk   = lane >> 4;   // K subgroup

  // ---- runtime XCD grouping + balance-gated fallback ----
  if (tid == 0) {
    // HW_REG_XCC_ID = id 20, offset 0, size 32 (m09: returns 0..7 on MI355X)
    unsigned xcc = (unsigned)__builtin_amdgcn_s_getreg(20 | (31 << 11)) & 15u;
    const unsigned slot = AFADDU(&ctrl[xcc], 1u);
    asm volatile("s_waitcnt vmcnt(0)" ::: "memory");   // claim performed at MALL
    AFADDU(&ctrl[16], 1u);
    while (ALOADU(&ctrl[16]) < (unsigned)NBLK) __builtin_amdgcn_s_sleep(8);
    bool ok = true;
    for (int i = 0; i < 16; ++i)
      ok &= (ALOADU(&ctrl[i]) == (i < 8 ? 32u : 0u));
    if (ok && slot < 32u) { s_g = (int)(xcc * 4u + (slot >> 3)); s_blk = (int)(slot & 7u); s_loc = 1; }
    else                  { s_g = (int)(blockIdx.x >> 3);        s_blk = (int)(blockIdx.x & 7); s_loc = 0; }
  }
  __syncthreads();
  const int  g   = s_g;
  const int  blk = s_blk;
  const bool loc = (s_loc != 0);

  // ---- persistent weight fragments: 2 col-tiles x 18 K-chunks ----
  s16x8 wf[2][18];
  float bias[2];
#pragma unroll
  for (int n = 0; n < 2; ++n) {
    const int c    = w * 32 + n * 16 + lrow;       // local gate-col 0..255
    const int grow = (c & 3) * HID + blk * UPB + (c >> 2);
#pragma unroll
    for (int kk = 0; kk < 16; ++kk) {
      const float* p = Whh + (size_t)grow * HID + kk * 32 + lk * 8;
      wf[n][kk] = pack8(*(const f32x4*)p, *(const f32x4*)(p + 4));
    }
#pragma unroll
    for (int kk = 0; kk < 2; ++kk) {
      const float* p = Wih + (size_t)grow * IND + kk * 32 + lk * 8;
      wf[n][16 + kk] = pack8(*(const f32x4*)p, *(const f32x4*)(p + 4));
    }
    bias[n] = bih[grow] + bhh[grow];
  }

  const bool is_gg = ((lrow & 3) == 2);           // tanh gate column
  const bool arow  = (lrow < BATCH_PG);           // lanes holding real A rows
  const bool prod  = (lk == 0) && ((lane & 3) == 0);

  // ---- in-kernel exchange-buffer init (both buffers; stale/replay-proof) ----
  if (prod) {
#pragma unroll
    for (int n = 0; n < 2; ++n) {
      const int gu = blk * UPB + w * 8 + n * 4 + (lrow >> 2);
      st_dual(hx + ((size_t)g << 10) + 2 * gu,                 loc, 0ull);            // rb0: tag0, h=0
      st_dual(hx + ((size_t)g << 10) + 2 * gu + 1,             loc, 0ull);
      st_dual(hx + ((size_t)(NGROUPS + g) << 10) + 2 * gu,     loc, 0xFFFFFFFFull);   // rb1: never-match
      st_dual(hx + ((size_t)(NGROUPS + g) << 10) + 2 * gu + 1, loc, 0xFFFFFFFFull);
    }
  }
  __syncthreads();   // drains every wave's init stores (vmcnt before barrier)
  if (tid == 0) {
    AFADDU(&ctrl[17], 1u);
    while (ALOADU(&ctrl[17]) < (unsigned)NBLK) __builtin_amdgcn_s_sleep(8);
  }
  __syncthreads();

  float cst[2][4] = {{0.f, 0.f, 0.f, 0.f}, {0.f, 0.f, 0.f, 0.f}};
  float hn[2][4];
  int scm = loc ? 0 : 1;   // 0 = sc0/local poll, 1 = sc1/MALL poll (sticky)

  // persistent A fragments: inactive lanes stay zero forever (masked loads)
  s16x8 ah[4] = {};
  s16x8 ax0 = {}, ax1 = {};

  const int xb = g * BATCH_PG + (lrow & 3);
  const float* xrow = x + (size_t)xb * (T_STEPS * IND) + lk * 8;

  // precomputed scatter constants (DPP-paired dword writes)
  const bool evn = (tid & 1) == 0;
  const int  ue  = tid & ~1;
  const int  sc_base = ((ue >> 3) << 4) + (ue & 7) * 2;   // slot*16 + byte
  const int  addr01 = (evn ? 0 : 1024) + (sc_base ^ (evn ? 0 : (4 << 4)));
  const int  addr23 = (evn ? 2048 : 3072) + (sc_base ^ (evn ? (8 << 4) : (12 << 4)));

  for (int t = 0; t < T_STEPS; ++t) {
    const int rb = t & 1;
    const unsigned tg = (unsigned)t;

    // x_t fragments (masked global loads; overlap the wait)
    if (arow) {
      const float* p = xrow + (size_t)t * IND;
      ax0 = pack8(*(const f32x4*)p,        *(const f32x4*)(p + 4));
      ax1 = pack8(*(const f32x4*)(p + 32), *(const f32x4*)(p + 36));
    }

    // poll own granule pair until tag == t (flag IS data)
    const u64_t* gp = hx + ((size_t)(rb * NGROUPS + g) << 10) + 2 * tid;
    u64_t v0 = 0, v1 = 0;
    if (scm == 0) {
      ld_pair_sc0(gp, v0, v1);
      int spins = 0;
      while ((unsigned)v0 != tg || (unsigned)v1 != tg) {
        if (__builtin_expect(++spins > POLL_CAP, 0)) { scm = 1; break; }  // sticky escape
        ld_pair_sc0(gp, v0, v1);
      }
    }
    if (scm == 1) {
      v0 = ALOADU(gp); v1 = ALOADU(gp + 1);
      while ((unsigned)v0 != tg || (unsigned)v1 != tg) {
        __builtin_amdgcn_s_sleep(1);
        if ((unsigned)v0 != tg) v0 = ALOADU(gp);
        if ((unsigned)v1 != tg) v1 = ALOADU(gp + 1);
      }
    }
    const unsigned hp0 = (unsigned)(v0 >> 32), hp1 = (unsigned)(v1 >> 32);

    // scatter: pair halves with quad neighbor -> 2 full-dword LDS writes
    {
      char* hb = (char*)hsm[rb];
      const unsigned q0 = qswap(hp0), q1 = qswap(hp1);
      const unsigned v01 = evn ? ((hp0 & 0xffffu) | (q0 << 16))
                               : ((q0 >> 16) | (hp0 & 0xffff0000u));
      const unsigned v23 = evn ? ((hp1 & 0xffffu) | (q1 << 16))
                               : ((q1 >> 16) | (hp1 & 0xffff0000u));
      *(unsigned*)(hb + addr01) = v01;
      *(unsigned*)(hb + addr23) = v23;
    }

    // x MFMAs seed 4 independent chains while the tile settles
    f32x4 acc00 = {0.f, 0.f, 0.f, 0.f}, acc01 = {0.f, 0.f, 0.f, 0.f};
    f32x4 acc10 = {0.f, 0.f, 0.f, 0.f}, acc11 = {0.f, 0.f, 0.f, 0.f};
    acc00 = __builtin_amdgcn_mfma_f32_16x16x32_bf16(ax0, wf[0][16], acc00, 0, 0, 0);
    acc01 = __builtin_amdgcn_mfma_f32_16x16x32_bf16(ax1, wf[0][17], acc01, 0, 0, 0);
    acc10 = __builtin_amdgcn_mfma_f32_16x16x32_bf16(ax0, wf[1][16], acc10, 0, 0, 0);
    acc11 = __builtin_amdgcn_mfma_f32_16x16x32_bf16(ax1, wf[1][17], acc11, 0, 0, 0);

    __syncthreads();

    // h MFMAs: masked reads (16 active lanes); two chains per col-tile
    const char* rowp = (const char*)hsm[rb] + lrow * 1024;
    const int rxor = lrow << 2;   // slot ^= (row*4); slot granule = 16B
#pragma unroll
    for (int kk4 = 0; kk4 < 4; ++kk4) {
      if (arow) {
#pragma unroll
        for (int j = 0; j < 4; ++j)
          ah[j] = *(const s16x8*)(rowp + (((16 * kk4 + 4 * j + lk) ^ rxor) << 4));
      }
#pragma unroll
      for (int j = 0; j < 4; ++j) {
        const int kk = kk4 * 4 + j;
        if (kk4 < 2) {
          acc00 = __builtin_amdgcn_mfma_f32_16x16x32_bf16(ah[j], wf[0][kk], acc00, 0, 0, 0);
          acc10 = __builtin_amdgcn_mfma_f32_16x16x32_bf16(ah[j], wf[1][kk], acc10, 0, 0, 0);
        } else {
          acc01 = __builtin_amdgcn_mfma_f32_16x16x32_bf16(ah[j], wf[0][kk], acc01, 0, 0, 0);
          acc11 = __builtin_amdgcn_mfma_f32_16x16x32_bf16(ah[j], wf[1][kk], acc11, 0, 0, 0);
        }
      }
    }

    // gates: branchless nonlinearity + DPP quad broadcasts
#pragma unroll
    for (int n = 0; n < 2; ++n) {
      const f32x4 aA = n ? acc10 : acc00;
      const f32x4 aB = n ? acc11 : acc01;
#pragma unroll
      for (int r = 0; r < 4; ++r) {
        const float v  = (aA[r] + aB[r]) + bias[n];
        const float a  = is_gg ? (2.f * v) : (-v);
        const float e  = __expf(a);
        const float r1 = __builtin_amdgcn_rcpf(1.f + e);
        const float sg = is_gg ? (1.f - 2.f * r1) : r1;   // tanh or sigmoid
        const float vi = qbc<0x00>(sg);
        const float vf = qbc<0x55>(sg);
        const float vg = qbc<0xAA>(sg);
        const float vo = qbc<0xFF>(sg);
        const float c  = fmaf(vf, cst[n][r], vi * vg);
        cst[n][r] = c;
        const float th = 1.f - 2.f * __builtin_amdgcn_rcpf(1.f + __expf(2.f * c));
        hn[n][r] = vo * th;
      }
    }

    // producer lanes dual-store tagged granules (fire-and-forget)
    u64_t* op = hx + ((size_t)((rb ^ 1) * NGROUPS + g) << 10);
    const u64_t ntg = (u64_t)(unsigned)(t + 1);
    if (prod) {
#pragma unroll
      for (int n = 0; n < 2; ++n) {
        const int ul = w * 8 + n * 4 + (lrow >> 2);     // local unit 0..63
        const int gu = blk * UPB + ul;                  // global unit 0..511
        const unsigned p01 = (unsigned)f2bf(hn[n][0]) | ((unsigned)f2bf(hn[n][1]) << 16);
        const unsigned p23 = (unsigned)f2bf(hn[n][2]) | ((unsigned)f2bf(hn[n][3]) << 16);
        st_dual(op + 2 * gu,     loc, ntg | ((u64_t)p01 << 32));
        st_dual(op + 2 * gu + 1, loc, ntg | ((u64_t)p23 << 32));
        if (t == T_STEPS - 1) {
#pragma unroll
          for (int r = 0; r < 4; ++r) clsh[r][ul] = hn[n][r];
        }
      }
    }
  }

  // ---- classifier: per-block partials over its 64 units ----
  __syncthreads();
  if (w == 0) {
#pragma unroll
    for (int b = 0; b < BATCH_PG; ++b) {
      const float hv = clsh[b][lane];
      for (int cls = 0; cls < 10; ++cls) {
        float v = hv * Wcls[(size_t)cls * HID + blk * UPB + lane];
#pragma unroll
        for (int m = 32; m >= 1; m >>= 1) v += __shfl_xor(v, m);
        if (lane == 0) {
          if (blk == 0) v += bcls[cls];
          atomicAdd(&out[(g * BATCH_PG + b) * 10 + cls], v);
        }
      }
    }
  }
}

extern "C" void kernel_launch(void* const* d_in, const int* in_sizes, int n_in,
                              void* d_out, int out_size, void* d_ws, size_t ws_size,
                              hipStream_t stream) {
  const float* x    = (const float*)d_in[0];
  const float* Wih  = (const float*)d_in[1];
  const float* Whh  = (const float*)d_in[2];
  const float* bih  = (const float*)d_in[3];
  const float* bhh  = (const float*)d_in[4];
  const float* Wcls = (const float*)d_in[5];
  const float* bcls = (const float*)d_in[6];
  float* out = (float*)d_out;

  u64_t* hx       = (u64_t*)d_ws;                              // 512 KiB (kernel-inited)
  unsigned* ctrl  = (unsigned*)((uint8_t*)d_ws + 512 * 1024);  // 128 B

  // replay-safe re-init (hx is initialized IN-KERNEL through the owning cache domain)
  hipMemsetAsync(ctrl, 0, 128, stream);
  hipMemsetAsync(out, 0, (size_t)out_size * sizeof(float), stream);

  void* args[] = {&x, &Wih, &Whh, &bih, &bhh, &Wcls, &bcls, &out, &hx, &ctrl};
  hipError_t e = hipLaunchCooperativeKernel(
      reinterpret_cast<const void*>(&lstm_persist), dim3(NBLK),
      dim3(NTHREADS), args, 0, stream);
  if (e != hipSuccess) {
    lstm_persist<<<dim3(NBLK), dim3(NTHREADS), 0, stream>>>(
        x, Wih, Whh, bih, bhh, Wcls, bcls, out, hx, ctrl);
  }
}

// Round 8
// 1803.073 us; speedup vs baseline: 35.4112x; 35.4112x over previous
//
#include <hip/hip_runtime.h>
#include <stdint.h>

// LSTM (B=128, T=512, I=64, H=512) persistent kernel, round 8:
//  - REVERT to round-4 protocol (proven 1416us): 32 groups x 8 blocks, bid-based
//    grouping, tag-embedded u64 granules {u32 tag, 2xbf16} at MALL via relaxed
//    agent (sc1) atomics; host memset init. XCD-local transport is CLOSED
//    (r6/r7: sc0 loads don't bypass L1; atomics are throughput-dead for bulk).
//  - NEW: software-pipelined poll. Next-step granule loads are issued BEFORE
//    the producer stores, so the loop-top check waits vmcnt(4) (preloads only)
//    instead of vmcnt(0) (which also waited our own store acks ~1 MALL RT).
//    Preload RT hides under gates + backedge.
//  - x loads moved after poll success (latency hides under scatter+barrier).
//  - Keeps: DPP-paired dword LDS scatter (0 conflicts), masked b128 reads,
//    4 independent MFMA chains, branchless gates, LDS classifier.

#define T_STEPS 512
#define HID 512
#define IND 64
#define NGROUPS 32
#define BPG 8           // blocks per group
#define BATCH_PG 4      // batches per group
#define UPB 64          // hidden units per block
#define NTHREADS 512    // 8 waves
#define NBLK (NGROUPS * BPG)

typedef float f32x4 __attribute__((ext_vector_type(4)));
typedef short s16x8 __attribute__((ext_vector_type(8)));
typedef unsigned long long u64_t;

#define ALOADU(p)    __hip_atomic_load((p), __ATOMIC_RELAXED, __HIP_MEMORY_SCOPE_AGENT)
#define ASTOREU(p,v) __hip_atomic_store((p), (v), __ATOMIC_RELAXED, __HIP_MEMORY_SCOPE_AGENT)

__device__ inline unsigned short f2bf(float f) {
  uint32_t u = __builtin_bit_cast(uint32_t, f);
  u += 0x7fffu + ((u >> 16) & 1u);   // RNE (finite inputs)
  return (unsigned short)(u >> 16);
}

__device__ inline s16x8 pack8(f32x4 a, f32x4 b) {
  s16x8 r;
  r[0] = (short)f2bf(a[0]); r[1] = (short)f2bf(a[1]);
  r[2] = (short)f2bf(a[2]); r[3] = (short)f2bf(a[3]);
  r[4] = (short)f2bf(b[0]); r[5] = (short)f2bf(b[1]);
  r[6] = (short)f2bf(b[2]); r[7] = (short)f2bf(b[3]);
  return r;
}

template <int CTRL>
__device__ inline float qbc(float v) {   // quad_perm broadcast via DPP (VALU)
  int i = __builtin_bit_cast(int, v);
  return __builtin_bit_cast(float,
      __builtin_amdgcn_update_dpp(i, i, CTRL, 0xF, 0xF, false));
}

__device__ inline unsigned qswap(unsigned v) {  // quad_perm [1,0,3,2]
  int i = __builtin_bit_cast(int, v);
  return (unsigned)__builtin_amdgcn_update_dpp(i, i, 0xB1, 0xF, 0xF, false);
}

__global__ void __launch_bounds__(NTHREADS, 2)
lstm_persist(const float* __restrict__ x,   const float* __restrict__ Wih,
             const float* __restrict__ Whh, const float* __restrict__ bih,
             const float* __restrict__ bhh, const float* __restrict__ Wcls,
             const float* __restrict__ bcls, float* __restrict__ out,
             u64_t* __restrict__ hx)   // [2][NGROUPS][1024] granules, memset 0
{
  __shared__ unsigned short hsm[2][4 * HID];      // 2 x 4KB A-tile (rows 0..3)
  __shared__ float clsh[BATCH_PG][UPB];           // final-h for classifier

  const int g    = blockIdx.x >> 3;
  const int blk  = blockIdx.x & 7;
  const int tid  = threadIdx.x;
  const int w    = tid >> 6;
  const int lane = tid & 63;
  const int lrow = lane & 15;   // A row / D col
  const int lk   = lane >> 4;   // K subgroup

  // ---- persistent weight fragments: 2 col-tiles x 18 K-chunks ----
  s16x8 wf[2][18];
  float bias[2];
#pragma unroll
  for (int n = 0; n < 2; ++n) {
    const int c    = w * 32 + n * 16 + lrow;       // local gate-col 0..255
    const int grow = (c & 3) * HID + blk * UPB + (c >> 2);
#pragma unroll
    for (int kk = 0; kk < 16; ++kk) {
      const float* p = Whh + (size_t)grow * HID + kk * 32 + lk * 8;
      wf[n][kk] = pack8(*(const f32x4*)p, *(const f32x4*)(p + 4));
    }
#pragma unroll
    for (int kk = 0; kk < 2; ++kk) {
      const float* p = Wih + (size_t)grow * IND + kk * 32 + lk * 8;
      wf[n][16 + kk] = pack8(*(const f32x4*)p, *(const f32x4*)(p + 4));
    }
    bias[n] = bih[grow] + bhh[grow];
  }

  const bool is_gg = ((lrow & 3) == 2);           // tanh gate column
  const bool arow  = (lrow < BATCH_PG);           // lanes holding real A rows
  const bool prod  = (lk == 0) && ((lane & 3) == 0);
  float cst[2][4] = {{0.f, 0.f, 0.f, 0.f}, {0.f, 0.f, 0.f, 0.f}};
  float hn[2][4];

  // persistent A fragments: inactive lanes stay zero forever (masked loads)
  s16x8 ah[4] = {};
  s16x8 ax0 = {}, ax1 = {};

  const int xb = g * BATCH_PG + (lrow & 3);
  const float* xrow = x + (size_t)xb * (T_STEPS * IND) + lk * 8;

  // precomputed scatter constants (DPP-paired dword writes)
  const bool evn = (tid & 1) == 0;
  const int  ue  = tid & ~1;
  const int  sc_base = ((ue >> 3) << 4) + (ue & 7) * 2;   // slot*16 + byte
  const int  addr01 = (evn ? 0 : 1024) + (sc_base ^ (evn ? 0 : (4 << 4)));
  const int  addr23 = (evn ? 2048 : 3072) + (sc_base ^ (evn ? (8 << 4) : (12 << 4)));

  // ---- pre-loop peel: establish the pipelined {2 preloads, 4 stores} pattern.
  // The stored values are the same zeros host memset wrote (benign races).
  u64_t pre0, pre1;
  {
    const u64_t* gp0 = hx + ((size_t)g << 10) + 2 * tid;
    pre0 = ALOADU(gp0);
    pre1 = ALOADU(gp0 + 1);
    if (prod) {
      u64_t* op0 = hx + ((size_t)g << 10);
#pragma unroll
      for (int n = 0; n < 2; ++n) {
        const int gu = blk * UPB + w * 8 + n * 4 + (lrow >> 2);
        ASTOREU(op0 + 2 * gu, 0ull);
        ASTOREU(op0 + 2 * gu + 1, 0ull);
      }
    }
  }

  for (int t = 0; t < T_STEPS; ++t) {
    const int rb = t & 1;
    const unsigned tg = (unsigned)t;

    // first check uses the PRELOADED pair (compiler emits vmcnt(4): the 4
    // producer stores are younger, so we do NOT wait on our own store acks)
    const u64_t* gp = hx + ((size_t)(rb * NGROUPS + g) << 10) + 2 * tid;
    u64_t v0 = pre0, v1 = pre1;
    while ((unsigned)v0 != tg || (unsigned)v1 != tg) {
      __builtin_amdgcn_s_sleep(1);
      if ((unsigned)v0 != tg) v0 = ALOADU(gp);
      if ((unsigned)v1 != tg) v1 = ALOADU(gp + 1);
    }
    const unsigned hp0 = (unsigned)(v0 >> 32), hp1 = (unsigned)(v1 >> 32);

    // x_t fragments AFTER poll: latency hides under scatter + barrier
    if (arow) {
      const float* p = xrow + (size_t)t * IND;
      ax0 = pack8(*(const f32x4*)p,        *(const f32x4*)(p + 4));
      ax1 = pack8(*(const f32x4*)(p + 32), *(const f32x4*)(p + 36));
    }

    // scatter: pair halves with quad neighbor -> 2 full-dword LDS writes
    {
      char* hb = (char*)hsm[rb];
      const unsigned q0 = qswap(hp0), q1 = qswap(hp1);
      const unsigned v01 = evn ? ((hp0 & 0xffffu) | (q0 << 16))
                               : ((q0 >> 16) | (hp0 & 0xffff0000u));
      const unsigned v23 = evn ? ((hp1 & 0xffffu) | (q1 << 16))
                               : ((q1 >> 16) | (hp1 & 0xffff0000u));
      *(unsigned*)(hb + addr01) = v01;
      *(unsigned*)(hb + addr23) = v23;
    }

    // x MFMAs seed 4 independent chains while the tile settles
    f32x4 acc00 = {0.f, 0.f, 0.f, 0.f}, acc01 = {0.f, 0.f, 0.f, 0.f};
    f32x4 acc10 = {0.f, 0.f, 0.f, 0.f}, acc11 = {0.f, 0.f, 0.f, 0.f};
    acc00 = __builtin_amdgcn_mfma_f32_16x16x32_bf16(ax0, wf[0][16], acc00, 0, 0, 0);
    acc01 = __builtin_amdgcn_mfma_f32_16x16x32_bf16(ax1, wf[0][17], acc01, 0, 0, 0);
    acc10 = __builtin_amdgcn_mfma_f32_16x16x32_bf16(ax0, wf[1][16], acc10, 0, 0, 0);
    acc11 = __builtin_amdgcn_mfma_f32_16x16x32_bf16(ax1, wf[1][17], acc11, 0, 0, 0);

    __syncthreads();

    // h MFMAs: masked reads (16 active lanes); two chains per col-tile
    const char* rowp = (const char*)hsm[rb] + lrow * 1024;
    const int rxor = lrow << 2;   // slot ^= (row*4); slot granule = 16B
#pragma unroll
    for (int kk4 = 0; kk4 < 4; ++kk4) {
      if (arow) {
#pragma unroll
        for (int j = 0; j < 4; ++j)
          ah[j] = *(const s16x8*)(rowp + (((16 * kk4 + 4 * j + lk) ^ rxor) << 4));
      }
#pragma unroll
      for (int j = 0; j < 4; ++j) {
        const int kk = kk4 * 4 + j;
        if (kk4 < 2) {
          acc00 = __builtin_amdgcn_mfma_f32_16x16x32_bf16(ah[j], wf[0][kk], acc00, 0, 0, 0);
          acc10 = __builtin_amdgcn_mfma_f32_16x16x32_bf16(ah[j], wf[1][kk], acc10, 0, 0, 0);
        } else {
          acc01 = __builtin_amdgcn_mfma_f32_16x16x32_bf16(ah[j], wf[0][kk], acc01, 0, 0, 0);
          acc11 = __builtin_amdgcn_mfma_f32_16x16x32_bf16(ah[j], wf[1][kk], acc11, 0, 0, 0);
        }
      }
    }

    // gates: branchless nonlinearity + DPP quad broadcasts
#pragma unroll
    for (int n = 0; n < 2; ++n) {
      const f32x4 aA = n ? acc10 : acc00;
      const f32x4 aB = n ? acc11 : acc01;
#pragma unroll
      for (int r = 0; r < 4; ++r) {
        const float v  = (aA[r] + aB[r]) + bias[n];
        const float a  = is_gg ? (2.f * v) : (-v);
        const float e  = __expf(a);
        const float r1 = __builtin_amdgcn_rcpf(1.f + e);
        const float sg = is_gg ? (1.f - 2.f * r1) : r1;   // tanh or sigmoid
        const float vi = qbc<0x00>(sg);
        const float vf = qbc<0x55>(sg);
        const float vg = qbc<0xAA>(sg);
        const float vo = qbc<0xFF>(sg);
        const float c  = fmaf(vf, cst[n][r], vi * vg);
        cst[n][r] = c;
        const float th = 1.f - 2.f * __builtin_amdgcn_rcpf(1.f + __expf(2.f * c));
        hn[n][r] = vo * th;
      }
    }

    // PREISSUE next-step poll loads (before the stores -> loop-top check
    // waits only on these, not on our store acks; RT hides under backedge)
    const u64_t* gpn =
        hx + ((size_t)(((t + 1) & 1) * NGROUPS + g) << 10) + 2 * tid;
    pre0 = ALOADU(gpn);
    pre1 = ALOADU(gpn + 1);

    // producer lanes store tagged granules (fire-and-forget)
    u64_t* op = hx + ((size_t)((rb ^ 1) * NGROUPS + g) << 10);
    const u64_t ntg = (u64_t)(unsigned)(t + 1);
    if (prod) {
#pragma unroll
      for (int n = 0; n < 2; ++n) {
        const int ul = w * 8 + n * 4 + (lrow >> 2);     // local unit 0..63
        const int gu = blk * UPB + ul;                  // global unit 0..511
        const unsigned p01 = (unsigned)f2bf(hn[n][0]) | ((unsigned)f2bf(hn[n][1]) << 16);
        const unsigned p23 = (unsigned)f2bf(hn[n][2]) | ((unsigned)f2bf(hn[n][3]) << 16);
        ASTOREU(op + 2 * gu,     ntg | ((u64_t)p01 << 32));
        ASTOREU(op + 2 * gu + 1, ntg | ((u64_t)p23 << 32));
        if (t == T_STEPS - 1) {
#pragma unroll
          for (int r = 0; r < 4; ++r) clsh[r][ul] = hn[n][r];
        }
      }
    }
  }

  // ---- classifier: per-block partials over its 64 units ----
  __syncthreads();
  if (w == 0) {
#pragma unroll
    for (int b = 0; b < BATCH_PG; ++b) {
      const float hv = clsh[b][lane];
      for (int cls = 0; cls < 10; ++cls) {
        float v = hv * Wcls[(size_t)cls * HID + blk * UPB + lane];
#pragma unroll
        for (int m = 32; m >= 1; m >>= 1) v += __shfl_xor(v, m);
        if (lane == 0) {
          if (blk == 0) v += bcls[cls];
          atomicAdd(&out[(g * BATCH_PG + b) * 10 + cls], v);
        }
      }
    }
  }
}

extern "C" void kernel_launch(void* const* d_in, const int* in_sizes, int n_in,
                              void* d_out, int out_size, void* d_ws, size_t ws_size,
                              hipStream_t stream) {
  const float* x    = (const float*)d_in[0];
  const float* Wih  = (const float*)d_in[1];
  const float* Whh  = (const float*)d_in[2];
  const float* bih  = (const float*)d_in[3];
  const float* bhh  = (const float*)d_in[4];
  const float* Wcls = (const float*)d_in[5];
  const float* bcls = (const float*)d_in[6];
  float* out = (float*)d_out;

  u64_t* hx = (u64_t*)d_ws;   // [2][32][1024] u64 = 512 KiB

  // replay-safe re-init: zero tags (tag0 == step-0 data h=0) and output accum
  hipMemsetAsync(hx, 0, 2 * NGROUPS * 1024 * sizeof(u64_t), stream);
  hipMemsetAsync(out, 0, (size_t)out_size * sizeof(float), stream);

  void* args[] = {&x, &Wih, &Whh, &bih, &bhh, &Wcls, &bcls, &out, &hx};
  hipError_t e = hipLaunchCooperativeKernel(
      reinterpret_cast<const void*>(&lstm_persist), dim3(NBLK),
      dim3(NTHREADS), args, 0, stream);
  if (e != hipSuccess) {
    lstm_persist<<<dim3(NBLK), dim3(NTHREADS), 0, stream>>>(
        x, Wih, Whh, bih, bhh, Wcls, bcls, out, hx);
  }
}

// Round 9
// 1404.155 us; speedup vs baseline: 45.4715x; 1.2841x over previous
//
#include <hip/hip_runtime.h>
#include <stdint.h>

// LSTM (B=128, T=512, I=64, H=512) persistent kernel, round 9:
//  - base = round-4 protocol EXACTLY (proven 1416us best): 32 groups x 8 blocks,
//    tag-embedded u64 granules {u32 tag, 2xbf16} at MALL, relaxed agent atomics,
//    x-loads BEFORE poll, one barrier/step. (r5/r8 reorderings both regressed:
//    store-ack wait in first poll iter is HIDDEN time, don't fight it.)
//  - NEW (local cuts only, no protocol reorder):
//    (1) x pre-converted to bf16 by prep kernel into ws (ws_size-gated) ->
//        removes 48 f2bf VALU/step + halves x fetch bytes
//    (2) poll = ONE global_load_dwordx4 sc1 (early-clobber asm) -> 1 MALL
//        transaction/iter instead of 2; per-8B tags make tearing safe
//    (3) no s_sleep in poll (cadence is vmcnt-bound ~RT anyway)

#define T_STEPS 512
#define HID 512
#define IND 64
#define NGROUPS 32
#define BPG 8           // blocks per group
#define BATCH_PG 4      // batches per group
#define UPB 64          // hidden units per block
#define NTHREADS 512    // 8 waves
#define NBLK (NGROUPS * BPG)
#define XBF_OFF (512 * 1024)
#define XBF_ELEMS (128 * T_STEPS * IND)

typedef float f32x4 __attribute__((ext_vector_type(4)));
typedef short s16x8 __attribute__((ext_vector_type(8)));
typedef unsigned u32x4 __attribute__((ext_vector_type(4)));
typedef unsigned long long u64_t;

#define ALOADU(p)    __hip_atomic_load((p), __ATOMIC_RELAXED, __HIP_MEMORY_SCOPE_AGENT)
#define ASTOREU(p,v) __hip_atomic_store((p), (v), __ATOMIC_RELAXED, __HIP_MEMORY_SCOPE_AGENT)

__device__ inline unsigned short f2bf(float f) {
  uint32_t u = __builtin_bit_cast(uint32_t, f);
  u += 0x7fffu + ((u >> 16) & 1u);   // RNE (finite inputs)
  return (unsigned short)(u >> 16);
}

__device__ inline s16x8 pack8(f32x4 a, f32x4 b) {
  s16x8 r;
  r[0] = (short)f2bf(a[0]); r[1] = (short)f2bf(a[1]);
  r[2] = (short)f2bf(a[2]); r[3] = (short)f2bf(a[3]);
  r[4] = (short)f2bf(b[0]); r[5] = (short)f2bf(b[1]);
  r[6] = (short)f2bf(b[2]); r[7] = (short)f2bf(b[3]);
  return r;
}

template <int CTRL>
__device__ inline float qbc(float v) {   // quad_perm broadcast via DPP (VALU)
  int i = __builtin_bit_cast(int, v);
  return __builtin_bit_cast(float,
      __builtin_amdgcn_update_dpp(i, i, CTRL, 0xF, 0xF, false));
}

__device__ inline unsigned qswap(unsigned v) {  // quad_perm [1,0,3,2]
  int i = __builtin_bit_cast(int, v);
  return (unsigned)__builtin_amdgcn_update_dpp(i, i, 0xB1, 0xF, 0xF, false);
}

// one 16B sc1 (device-coherent, MALL) load of a granule pair. EARLY-CLOBBER.
__device__ inline void ld4_sc1(const u64_t* p, u64_t& a, u64_t& b) {
  u32x4 r;
  asm volatile("global_load_dwordx4 %0, %1, off sc1\n\ts_waitcnt vmcnt(0)"
               : "=&v"(r) : "v"(p) : "memory");
  a = ((u64_t)r[1] << 32) | r[0];
  b = ((u64_t)r[3] << 32) | r[2];
}

// prep: x f32 -> bf16 (same [b][t][i] layout)
__global__ void __launch_bounds__(256) xconv(const float* __restrict__ x,
                                             unsigned short* __restrict__ xb) {
  const int stride = gridDim.x * blockDim.x;
  for (int i = blockIdx.x * blockDim.x + threadIdx.x; i < XBF_ELEMS / 4; i += stride) {
    const f32x4 v = ((const f32x4*)x)[i];
    u64_t o = (u64_t)f2bf(v[0]) | ((u64_t)f2bf(v[1]) << 16) |
              ((u64_t)f2bf(v[2]) << 32) | ((u64_t)f2bf(v[3]) << 48);
    ((u64_t*)xb)[i] = o;
  }
}

template <bool XBF>
__global__ void __launch_bounds__(NTHREADS, 2)
lstm_persist(const float* __restrict__ x,   const float* __restrict__ Wih,
             const float* __restrict__ Whh, const float* __restrict__ bih,
             const float* __restrict__ bhh, const float* __restrict__ Wcls,
             const float* __restrict__ bcls, float* __restrict__ out,
             u64_t* __restrict__ hx,                 // [2][NGROUPS][1024], memset 0
             const unsigned short* __restrict__ xbf) // bf16 x or null
{
  __shared__ unsigned short hsm[2][4 * HID];      // 2 x 4KB A-tile (rows 0..3)
  __shared__ float clsh[BATCH_PG][UPB];           // final-h for classifier

  const int g    = blockIdx.x >> 3;
  const int blk  = blockIdx.x & 7;
  const int tid  = threadIdx.x;
  const int w    = tid >> 6;
  const int lane = tid & 63;
  const int lrow = lane & 15;   // A row / D col
  const int lk   = lane >> 4;   // K subgroup

  // ---- persistent weight fragments: 2 col-tiles x 18 K-chunks ----
  s16x8 wf[2][18];
  float bias[2];
#pragma unroll
  for (int n = 0; n < 2; ++n) {
    const int c    = w * 32 + n * 16 + lrow;       // local gate-col 0..255
    const int grow = (c & 3) * HID + blk * UPB + (c >> 2);
#pragma unroll
    for (int kk = 0; kk < 16; ++kk) {
      const float* p = Whh + (size_t)grow * HID + kk * 32 + lk * 8;
      wf[n][kk] = pack8(*(const f32x4*)p, *(const f32x4*)(p + 4));
    }
#pragma unroll
    for (int kk = 0; kk < 2; ++kk) {
      const float* p = Wih + (size_t)grow * IND + kk * 32 + lk * 8;
      wf[n][16 + kk] = pack8(*(const f32x4*)p, *(const f32x4*)(p + 4));
    }
    bias[n] = bih[grow] + bhh[grow];
  }

  const bool is_gg = ((lrow & 3) == 2);           // tanh gate column
  const bool arow  = (lrow < BATCH_PG);           // lanes holding real A rows
  const bool prod  = (lk == 0) && ((lane & 3) == 0);
  float cst[2][4] = {{0.f, 0.f, 0.f, 0.f}, {0.f, 0.f, 0.f, 0.f}};
  float hn[2][4];

  // persistent A fragments: inactive lanes stay zero forever (masked loads)
  s16x8 ah[4] = {};
  s16x8 ax0 = {}, ax1 = {};

  const int xb = g * BATCH_PG + (lrow & 3);
  const float* xrow = x + (size_t)xb * (T_STEPS * IND) + lk * 8;
  const unsigned short* xbrow = XBF ? (xbf + (size_t)xb * (T_STEPS * IND) + lk * 8)
                                    : (const unsigned short*)nullptr;

  // precomputed scatter constants (DPP-paired dword writes)
  const bool evn = (tid & 1) == 0;
  const int  ue  = tid & ~1;
  const int  sc_base = ((ue >> 3) << 4) + (ue & 7) * 2;   // slot*16 + byte
  const int  addr01 = (evn ? 0 : 1024) + (sc_base ^ (evn ? 0 : (4 << 4)));
  const int  addr23 = (evn ? 2048 : 3072) + (sc_base ^ (evn ? (8 << 4) : (12 << 4)));

  for (int t = 0; t < T_STEPS; ++t) {
    const int rb = t & 1;
    const unsigned tg = (unsigned)t;

    // x_t fragments BEFORE poll (latency hides under the spin)
    if (arow) {
      if (XBF) {
        ax0 = *(const s16x8*)(xbrow + (size_t)t * IND);
        ax1 = *(const s16x8*)(xbrow + (size_t)t * IND + 32);
      } else {
        const float* p = xrow + (size_t)t * IND;
        ax0 = pack8(*(const f32x4*)p,        *(const f32x4*)(p + 4));
        ax1 = pack8(*(const f32x4*)(p + 32), *(const f32x4*)(p + 36));
      }
    }

    // poll own granule pair until tag == t (flag IS data); 1 transaction/iter
    const u64_t* gp = hx + ((size_t)(rb * NGROUPS + g) << 10) + 2 * tid;
    u64_t v0, v1;
    ld4_sc1(gp, v0, v1);
    while ((unsigned)v0 != tg || (unsigned)v1 != tg) ld4_sc1(gp, v0, v1);
    const unsigned hp0 = (unsigned)(v0 >> 32), hp1 = (unsigned)(v1 >> 32);

    // scatter: pair halves with quad neighbor -> 2 full-dword LDS writes
    {
      char* hb = (char*)hsm[rb];
      const unsigned q0 = qswap(hp0), q1 = qswap(hp1);
      const unsigned v01 = evn ? ((hp0 & 0xffffu) | (q0 << 16))
                               : ((q0 >> 16) | (hp0 & 0xffff0000u));
      const unsigned v23 = evn ? ((hp1 & 0xffffu) | (q1 << 16))
                               : ((q1 >> 16) | (hp1 & 0xffff0000u));
      *(unsigned*)(hb + addr01) = v01;
      *(unsigned*)(hb + addr23) = v23;
    }

    // x MFMAs seed 4 independent chains while the tile settles
    f32x4 acc00 = {0.f, 0.f, 0.f, 0.f}, acc01 = {0.f, 0.f, 0.f, 0.f};
    f32x4 acc10 = {0.f, 0.f, 0.f, 0.f}, acc11 = {0.f, 0.f, 0.f, 0.f};
    acc00 = __builtin_amdgcn_mfma_f32_16x16x32_bf16(ax0, wf[0][16], acc00, 0, 0, 0);
    acc01 = __builtin_amdgcn_mfma_f32_16x16x32_bf16(ax1, wf[0][17], acc01, 0, 0, 0);
    acc10 = __builtin_amdgcn_mfma_f32_16x16x32_bf16(ax0, wf[1][16], acc10, 0, 0, 0);
    acc11 = __builtin_amdgcn_mfma_f32_16x16x32_bf16(ax1, wf[1][17], acc11, 0, 0, 0);

    __syncthreads();

    // h MFMAs: masked reads (16 active lanes); two chains per col-tile
    const char* rowp = (const char*)hsm[rb] + lrow * 1024;
    const int rxor = lrow << 2;   // slot ^= (row*4); slot granule = 16B
#pragma unroll
    for (int kk4 = 0; kk4 < 4; ++kk4) {
      if (arow) {
#pragma unroll
        for (int j = 0; j < 4; ++j)
          ah[j] = *(const s16x8*)(rowp + (((16 * kk4 + 4 * j + lk) ^ rxor) << 4));
      }
#pragma unroll
      for (int j = 0; j < 4; ++j) {
        const int kk = kk4 * 4 + j;
        if (kk4 < 2) {
          acc00 = __builtin_amdgcn_mfma_f32_16x16x32_bf16(ah[j], wf[0][kk], acc00, 0, 0, 0);
          acc10 = __builtin_amdgcn_mfma_f32_16x16x32_bf16(ah[j], wf[1][kk], acc10, 0, 0, 0);
        } else {
          acc01 = __builtin_amdgcn_mfma_f32_16x16x32_bf16(ah[j], wf[0][kk], acc01, 0, 0, 0);
          acc11 = __builtin_amdgcn_mfma_f32_16x16x32_bf16(ah[j], wf[1][kk], acc11, 0, 0, 0);
        }
      }
    }

    // gates: branchless nonlinearity + DPP quad broadcasts
#pragma unroll
    for (int n = 0; n < 2; ++n) {
      const f32x4 aA = n ? acc10 : acc00;
      const f32x4 aB = n ? acc11 : acc01;
#pragma unroll
      for (int r = 0; r < 4; ++r) {
        const float v  = (aA[r] + aB[r]) + bias[n];
        const float a  = is_gg ? (2.f * v) : (-v);
        const float e  = __expf(a);
        const float r1 = __builtin_amdgcn_rcpf(1.f + e);
        const float sg = is_gg ? (1.f - 2.f * r1) : r1;   // tanh or sigmoid
        const float vi = qbc<0x00>(sg);
        const float vf = qbc<0x55>(sg);
        const float vg = qbc<0xAA>(sg);
        const float vo = qbc<0xFF>(sg);
        const float c  = fmaf(vf, cst[n][r], vi * vg);
        cst[n][r] = c;
        const float th = 1.f - 2.f * __builtin_amdgcn_rcpf(1.f + __expf(2.f * c));
        hn[n][r] = vo * th;
      }
    }

    // producer lanes store tagged granules (fire-and-forget)
    u64_t* op = hx + ((size_t)((rb ^ 1) * NGROUPS + g) << 10);
    const u64_t ntg = (u64_t)(unsigned)(t + 1);
    if (prod) {
#pragma unroll
      for (int n = 0; n < 2; ++n) {
        const int ul = w * 8 + n * 4 + (lrow >> 2);     // local unit 0..63
        const int gu = blk * UPB + ul;                  // global unit 0..511
        const unsigned p01 = (unsigned)f2bf(hn[n][0]) | ((unsigned)f2bf(hn[n][1]) << 16);
        const unsigned p23 = (unsigned)f2bf(hn[n][2]) | ((unsigned)f2bf(hn[n][3]) << 16);
        ASTOREU(op + 2 * gu,     ntg | ((u64_t)p01 << 32));
        ASTOREU(op + 2 * gu + 1, ntg | ((u64_t)p23 << 32));
        if (t == T_STEPS - 1) {
#pragma unroll
          for (int r = 0; r < 4; ++r) clsh[r][ul] = hn[n][r];
        }
      }
    }
  }

  // ---- classifier: per-block partials over its 64 units ----
  __syncthreads();
  if (w == 0) {
#pragma unroll
    for (int b = 0; b < BATCH_PG; ++b) {
      const float hv = clsh[b][lane];
      for (int cls = 0; cls < 10; ++cls) {
        float v = hv * Wcls[(size_t)cls * HID + blk * UPB + lane];
#pragma unroll
        for (int m = 32; m >= 1; m >>= 1) v += __shfl_xor(v, m);
        if (lane == 0) {
          if (blk == 0) v += bcls[cls];
          atomicAdd(&out[(g * BATCH_PG + b) * 10 + cls], v);
        }
      }
    }
  }
}

extern "C" void kernel_launch(void* const* d_in, const int* in_sizes, int n_in,
                              void* d_out, int out_size, void* d_ws, size_t ws_size,
                              hipStream_t stream) {
  const float* x    = (const float*)d_in[0];
  const float* Wih  = (const float*)d_in[1];
  const float* Whh  = (const float*)d_in[2];
  const float* bih  = (const float*)d_in[3];
  const float* bhh  = (const float*)d_in[4];
  const float* Wcls = (const float*)d_in[5];
  const float* bcls = (const float*)d_in[6];
  float* out = (float*)d_out;

  u64_t* hx = (u64_t*)d_ws;   // [2][32][1024] u64 = 512 KiB
  const bool use_xbf = ws_size >= (size_t)XBF_OFF + (size_t)XBF_ELEMS * 2;
  unsigned short* xbf = use_xbf ? (unsigned short*)((uint8_t*)d_ws + XBF_OFF) : nullptr;

  // replay-safe re-init: zero tags (tag0 == step-0 data h=0) and output accum
  hipMemsetAsync(hx, 0, 2 * NGROUPS * 1024 * sizeof(u64_t), stream);
  hipMemsetAsync(out, 0, (size_t)out_size * sizeof(float), stream);
  if (use_xbf) xconv<<<dim3(2048), dim3(256), 0, stream>>>(x, xbf);

  const unsigned short* xbfc = xbf;
  void* args[] = {&x, &Wih, &Whh, &bih, &bhh, &Wcls, &bcls, &out, &hx, &xbfc};
  if (use_xbf) {
    hipError_t e = hipLaunchCooperativeKernel(
        reinterpret_cast<const void*>(&lstm_persist<true>), dim3(NBLK),
        dim3(NTHREADS), args, 0, stream);
    if (e != hipSuccess)
      lstm_persist<true><<<dim3(NBLK), dim3(NTHREADS), 0, stream>>>(
          x, Wih, Whh, bih, bhh, Wcls, bcls, out, hx, xbfc);
  } else {
    hipError_t e = hipLaunchCooperativeKernel(
        reinterpret_cast<const void*>(&lstm_persist<false>), dim3(NBLK),
        dim3(NTHREADS), args, 0, stream);
    if (e != hipSuccess)
      lstm_persist<false><<<dim3(NBLK), dim3(NTHREADS), 0, stream>>>(
          x, Wih, Whh, bih, bhh, Wcls, bcls, out, hx, xbfc);
  }
}